// Round 8
// baseline (587.725 us; speedup 1.0000x reference)
//
#include <hip/hip_runtime.h>
#include <hip/hip_cooperative_groups.h>
#include <math.h>

namespace cg = cooperative_groups;

#define INDIM 128
#define HC 256
#define NH 4
#define CAP 128

typedef unsigned short ushort_t;

__device__ __forceinline__ unsigned int f2bf_u(float f) {
  unsigned int u = __float_as_uint(f);
  return (u + 0x7FFFu + ((u >> 16) & 1u)) >> 16;
}
__device__ __forceinline__ float bf2f(ushort_t u) {
  return __uint_as_float(((unsigned int)u) << 16);
}

// One cooperative kernel, 6 phases:
// P0 zero cnt/sums | P1 bucket scatter + GEMM/att | P2 node softmax+aggregate
// P3 alpha + BN1 stats | P4 BN2 stats | P5 final BN + transposed store
__global__ __launch_bounds__(256, 4) void mega_kernel(
    const float* __restrict__ x, const int* __restrict__ src,
    const int* __restrict__ dst, const float* __restrict__ W,
    const float* __restrict__ att_s, const float* __restrict__ att_d,
    const float* __restrict__ bias, const float* __restrict__ gamma,
    const float* __restrict__ beta, ushort_t* __restrict__ xpb,
    float* __restrict__ x1, float* __restrict__ a_src,
    float* __restrict__ a_dst, float* __restrict__ mdi,
    int* __restrict__ cnt, float* __restrict__ sums,
    int* __restrict__ bucket, float* __restrict__ out_heads,
    float* __restrict__ out_alpha, int N, int E) {
  cg::grid_group grid = cg::this_grid();
  const int tid = threadIdx.x;
  const int bid = blockIdx.x;
  const int G = gridDim.x;
  const int gtid = bid * 256 + tid;
  const int GT = G * 256;
  const int lane = tid & 63;
  const int wv = tid >> 6;

  // 8KB shared, reused across phases
  __shared__ __align__(16) char smraw[16 * INDIM * 4];
  float* xs = (float*)smraw;                                // P1: 16x128 tile
  float* alpha_lds = (float*)smraw;                         // P2: NH*CAP floats
  int* src_lds = (int*)(smraw + NH * CAP * 4);              // P2: CAP ints
  float* m_s = (float*)(smraw + NH * CAP * 4 + CAP * 4);    // P2: NH
  float* d_s = m_s + NH;                                    // P2: NH

  // ---------------- P0: zero cnt + sums(4*HC) ----------------
  for (int i = gtid; i < N + 4 * HC; i += GT) {
    if (i < N) cnt[i] = 0;
    else sums[i - N] = 0.f;
  }
  __threadfence();
  grid.sync();

  // ---------------- P1: bucket scatter + GEMM/att ----------------
  for (int e = gtid; e < E; e += GT) {
    int d = dst[e];
    int pos = atomicAdd(&cnt[d], 1);
    if (pos < CAP) bucket[(size_t)d * CAP + pos] = src[e];
  }
  {
    const int col = lane * 4;
    const int row0 = wv * 4;
    int ntiles = (N + 15) / 16;
    for (int t = bid; t < ntiles; t += G) {
      int n0 = t * 16;
      int nrows = min(16, N - n0);
      if (nrows == 16) {
        const float4* xg = (const float4*)(x + (size_t)n0 * INDIM);
        float4* xs4 = (float4*)xs;
        xs4[tid] = xg[tid];
        xs4[tid + 256] = xg[tid + 256];
      } else {
        for (int i = tid; i < 16 * INDIM; i += 256) {
          int r = i / INDIM;
          xs[i] = (r < nrows) ? x[(size_t)(n0 + r) * INDIM + (i % INDIM)] : 0.f;
        }
      }
      __syncthreads();
      float4 a0 = {0.f, 0.f, 0.f, 0.f}, a1 = a0, a2 = a0, a3 = a0;
      for (int k0 = 0; k0 < INDIM; k0 += 4) {
        float4 w0 = *(const float4*)&W[(size_t)(k0 + 0) * HC + col];
        float4 w1 = *(const float4*)&W[(size_t)(k0 + 1) * HC + col];
        float4 w2 = *(const float4*)&W[(size_t)(k0 + 2) * HC + col];
        float4 w3 = *(const float4*)&W[(size_t)(k0 + 3) * HC + col];
        float4 x0 = *(const float4*)&xs[(row0 + 0) * INDIM + k0];
        float4 x1v = *(const float4*)&xs[(row0 + 1) * INDIM + k0];
        float4 x2v = *(const float4*)&xs[(row0 + 2) * INDIM + k0];
        float4 x3v = *(const float4*)&xs[(row0 + 3) * INDIM + k0];
#define UPD(A, XV)                                                        \
        A.x = fmaf(XV.w, w3.x, fmaf(XV.z, w2.x, fmaf(XV.y, w1.x, fmaf(XV.x, w0.x, A.x)))); \
        A.y = fmaf(XV.w, w3.y, fmaf(XV.z, w2.y, fmaf(XV.y, w1.y, fmaf(XV.x, w0.y, A.y)))); \
        A.z = fmaf(XV.w, w3.z, fmaf(XV.z, w2.z, fmaf(XV.y, w1.z, fmaf(XV.x, w0.z, A.z)))); \
        A.w = fmaf(XV.w, w3.w, fmaf(XV.z, w2.w, fmaf(XV.y, w1.w, fmaf(XV.x, w0.w, A.w))))
        UPD(a0, x0);
        UPD(a1, x1v);
        UPD(a2, x2v);
        UPD(a3, x3v);
#undef UPD
      }
      float4 as4 = *(const float4*)&att_s[col];
      float4 ad4 = *(const float4*)&att_d[col];
      int h = lane >> 4;
      float4* accp[4] = {&a0, &a1, &a2, &a3};
#pragma unroll
      for (int r = 0; r < 4; ++r) {
        int row = row0 + r;
        if (row >= nrows) break;
        float4 a = *accp[r];
        uint2 pk;
        pk.x = f2bf_u(a.x) | (f2bf_u(a.y) << 16);
        pk.y = f2bf_u(a.z) | (f2bf_u(a.w) << 16);
        *(uint2*)&xpb[(size_t)(n0 + row) * HC + col] = pk;
        float ps = a.x * as4.x + a.y * as4.y + a.z * as4.z + a.w * as4.w;
        float pd = a.x * ad4.x + a.y * ad4.y + a.z * ad4.z + a.w * ad4.w;
#pragma unroll
        for (int o = 8; o > 0; o >>= 1) {
          ps += __shfl_xor(ps, o);
          pd += __shfl_xor(pd, o);
        }
        if ((lane & 15) == 0) {
          a_src[(n0 + row) * NH + h] = ps;
          a_dst[(n0 + row) * NH + h] = pd;
        }
      }
      __syncthreads();  // xs reused next tile
    }
  }
  __threadfence();
  grid.sync();

  // ---------------- P2: per-node softmax + bf16 gather aggregate ----------------
  {
    float bv = bias[tid];
    for (int n = bid; n < N; n += G) {
      int deg = min(cnt[n], CAP);
      if (deg == 0) { x1[(size_t)n * HC + tid] = bv; continue; }
      const int* brow = bucket + (size_t)n * CAP;

      // Phase A: wave wv = head wv online softmax (deg<=128 -> <=2 iters)
      {
        int h = wv;
        float adst = a_dst[n * NH + h];
        float m = -INFINITY, s = 0.f;
        for (int i = lane; i < deg; i += 64) {
          int sidx = brow[i];
          float l = a_src[sidx * NH + h] + adst;
          l = (l >= 0.f) ? l : 0.2f * l;
          if (l > m) { s = s * __expf(m - l) + 1.f; m = l; }
          else s += __expf(l - m);
        }
#pragma unroll
        for (int o = 32; o > 0; o >>= 1) {
          float m2 = __shfl_xor(m, o);
          float s2 = __shfl_xor(s, o);
          float M = fmaxf(m, m2);
          float sa = (m > -INFINITY) ? s * __expf(m - M) : 0.f;
          float sb = (m2 > -INFINITY) ? s2 * __expf(m2 - M) : 0.f;
          m = M; s = sa + sb;
        }
        if (lane == 0) { m_s[h] = m; d_s[h] = s + 1e-16f; }
      }
      __syncthreads();

      float m_r[NH], dinv_r[NH], adst_r[NH];
#pragma unroll
      for (int h = 0; h < NH; ++h) {
        m_r[h] = m_s[h];
        dinv_r[h] = 1.0f / d_s[h];
        adst_r[h] = a_dst[n * NH + h];
      }
      if (tid < NH) mdi[(size_t)n * 12 + tid] = m_r[tid];
      else if (tid < 2 * NH) mdi[(size_t)n * 12 + tid] = dinv_r[tid - NH];
      else if (tid < 3 * NH) mdi[(size_t)n * 12 + tid] = adst_r[tid - 2 * NH];

      int cpad = (deg + 3) & ~3;
      if (tid < deg) {
        int sidx = brow[tid];
        src_lds[tid] = sidx;
        float4 as4 = *(const float4*)&a_src[sidx * NH];
        const float* ap = (const float*)&as4;
#pragma unroll
        for (int h = 0; h < NH; ++h) {
          float l = ap[h] + adst_r[h];
          l = (l >= 0.f) ? l : 0.2f * l;
          alpha_lds[h * CAP + tid] = __expf(l - m_r[h]) * dinv_r[h];
        }
      } else if (tid < cpad) {
        src_lds[tid] = 0;
#pragma unroll
        for (int h = 0; h < NH; ++h) alpha_lds[h * CAP + tid] = 0.f;
      }
      __syncthreads();

      float acc0 = 0.f, acc1 = 0.f, acc2 = 0.f, acc3 = 0.f;
      int hbase = wv * CAP;
      for (int i = 0; i < cpad; i += 4) {
        float4 a4 = *(const float4*)&alpha_lds[hbase + i];
        int4 s4 = *(const int4*)&src_lds[i];
        ushort_t u0 = xpb[(size_t)s4.x * HC + tid];
        ushort_t u1 = xpb[(size_t)s4.y * HC + tid];
        ushort_t u2 = xpb[(size_t)s4.z * HC + tid];
        ushort_t u3 = xpb[(size_t)s4.w * HC + tid];
        acc0 = fmaf(a4.x, bf2f(u0), acc0);
        acc1 = fmaf(a4.y, bf2f(u1), acc1);
        acc2 = fmaf(a4.z, bf2f(u2), acc2);
        acc3 = fmaf(a4.w, bf2f(u3), acc3);
      }
      x1[(size_t)n * HC + tid] = (acc0 + acc1) + (acc2 + acc3) + bv;
      __syncthreads();  // LDS reused next node
    }
  }
  __threadfence();
  grid.sync();

  // ---------------- P3: edge-order alpha + BN1 stats ----------------
  for (int e = gtid; e < E; e += GT) {
    int s = src[e], d = dst[e];
    float4 as4 = *(const float4*)&a_src[s * NH];
    const float* md = &mdi[(size_t)d * 12];
    float4 m4 = *(const float4*)md;
    float4 di4 = *(const float4*)(md + 4);
    float4 ad4 = *(const float4*)(md + 8);
    const float* ap = (const float*)&as4;
    const float* mp = (const float*)&m4;
    const float* dp = (const float*)&di4;
    const float* adp = (const float*)&ad4;
    float4 av;
    float* avp = (float*)&av;
#pragma unroll
    for (int h = 0; h < NH; ++h) {
      float l = ap[h] + adp[h];
      l = (l >= 0.f) ? l : 0.2f * l;
      avp[h] = __expf(l - mp[h]) * dp[h];
    }
    *(float4*)&out_alpha[(size_t)e * NH] = av;
  }
  {
    float s = 0.f, q = 0.f;
    for (int r = bid; r < N; r += G) {
      float v = x1[(size_t)r * HC + tid];
      s += v; q = fmaf(v, v, q);
    }
    atomicAdd(&sums[tid], s);
    atomicAdd(&sums[HC + tid], q);
  }
  __threadfence();
  grid.sync();

  // ---------------- P4: BN2 stats over elu(bn1(x1)) ----------------
  {
    float mu = sums[tid] * (1.f / N);
    float var = sums[HC + tid] * (1.f / N) - mu * mu;
    float inv = rsqrtf(var + 1e-5f);
    float g = gamma[tid], b = beta[tid];
    float s = 0.f, q = 0.f;
    for (int r = bid; r < N; r += G) {
      float v = x1[(size_t)r * HC + tid];
      float x2 = fmaf((v - mu) * inv, g, b);
      float e = x2 > 0.f ? x2 : expm1f(x2);
      s += e; q = fmaf(e, e, q);
    }
    atomicAdd(&sums[2 * HC + tid], s);
    atomicAdd(&sums[3 * HC + tid], q);
  }
  __threadfence();
  grid.sync();

  // ---------------- P5: final BN + transposed store ----------------
  {
    float mu1 = sums[tid] * (1.f / N);
    float var1 = sums[HC + tid] * (1.f / N) - mu1 * mu1;
    float inv1 = rsqrtf(var1 + 1e-5f);
    float mu2 = sums[2 * HC + tid] * (1.f / N);
    float var2 = sums[3 * HC + tid] * (1.f / N) - mu2 * mu2;
    float inv2 = rsqrtf(var2 + 1e-5f);
    float g = gamma[tid], b = beta[tid];
    int h = tid >> 6, c = tid & 63;
    for (int r = bid; r < N; r += G) {
      float v = x1[(size_t)r * HC + tid];
      float x2 = fmaf((v - mu1) * inv1, g, b);
      float e = x2 > 0.f ? x2 : expm1f(x2);
      out_heads[(size_t)h * N * 64 + (size_t)r * 64 + c] = fmaf((e - mu2) * inv2, g, b);
    }
  }
}

extern "C" void kernel_launch(void* const* d_in, const int* in_sizes, int n_in,
                              void* d_out, int out_size, void* d_ws, size_t ws_size,
                              hipStream_t stream) {
  const float* x     = (const float*)d_in[0];
  const int*   edge  = (const int*)d_in[1];
  const float* W     = (const float*)d_in[2];
  const float* att_s = (const float*)d_in[3];
  const float* att_d = (const float*)d_in[4];
  const float* bias  = (const float*)d_in[5];
  const float* gamma = (const float*)d_in[6];
  const float* beta  = (const float*)d_in[7];

  int N = in_sizes[0] / INDIM;
  int E = in_sizes[1] / 2;
  const int* src = edge;
  const int* dst = edge + E;

  char* ws = (char*)d_ws;
  size_t o = 0;
  auto alloc = [&](size_t bytes) {
    void* p = ws + o;
    o += (bytes + 255) & ~(size_t)255;
    return p;
  };
  ushort_t* xpb = (ushort_t*)alloc((size_t)N * HC * 2);
  float* x1     = (float*)alloc((size_t)N * HC * 4);
  float* a_src  = (float*)alloc((size_t)N * NH * 4);
  float* a_dst  = (float*)alloc((size_t)N * NH * 4);
  float* mdi    = (float*)alloc((size_t)N * 12 * 4);
  int*   cnt    = (int*)alloc((size_t)N * 4);
  float* sums   = (float*)alloc(4 * HC * 4);
  int*   bucket = (int*)alloc((size_t)N * CAP * 4);

  float* out_heads = (float*)d_out;
  float* out_alpha = out_heads + (size_t)NH * N * 64;

  // grid size: guaranteed co-resident (occupancy-query x CU count), capped
  int maxb = 4;
  hipOccupancyMaxActiveBlocksPerMultiprocessor(&maxb, mega_kernel, 256, 0);
  if (maxb < 1) maxb = 1;
  hipDeviceProp_t props;
  int dev = 0;
  hipGetDevice(&dev);
  hipGetDeviceProperties(&props, dev);
  int ncu = props.multiProcessorCount;
  if (ncu < 1) ncu = 256;
  long long cap = (long long)maxb * ncu;
  int G = (int)(cap < 1024 ? cap : 1024);

  void* args[] = {
      (void*)&x, (void*)&src, (void*)&dst, (void*)&W, (void*)&att_s,
      (void*)&att_d, (void*)&bias, (void*)&gamma, (void*)&beta, (void*)&xpb,
      (void*)&x1, (void*)&a_src, (void*)&a_dst, (void*)&mdi, (void*)&cnt,
      (void*)&sums, (void*)&bucket, (void*)&out_heads, (void*)&out_alpha,
      (void*)&N, (void*)&E};
  hipLaunchCooperativeKernel((const void*)mega_kernel, dim3(G), dim3(256),
                             args, 0, stream);
}

// Round 9
// 125.022 us; speedup vs baseline: 4.7010x; 4.7010x over previous
//
#include <hip/hip_runtime.h>
#include <math.h>

#define INDIM 128
#define HC 256
#define NH 4
#define CAP 128
#define BROWS 20

typedef unsigned short ushort_t;

__device__ __forceinline__ unsigned int f2bf_u(float f) {
  unsigned int u = __float_as_uint(f);
  return (u + 0x7FFFu + ((u >> 16) & 1u)) >> 16;
}
__device__ __forceinline__ float bf2f(ushort_t u) {
  return __uint_as_float(((unsigned int)u) << 16);
}

// --- GEMM (16x256 tile, 4x4 reg tile/thread) + att coeffs + bucket scatter ---
__global__ __launch_bounds__(256) void gemm_att_bucket_kernel(
    const float* __restrict__ x, const float* __restrict__ W,
    const float* __restrict__ att_s, const float* __restrict__ att_d,
    const int* __restrict__ src, const int* __restrict__ dst,
    int* __restrict__ cnt, int* __restrict__ bucket, int E, int epb,
    ushort_t* __restrict__ xpb, float* __restrict__ a_src,
    float* __restrict__ a_dst, int N) {
  constexpr int RM = 16;
  __shared__ __align__(16) float xs[RM * INDIM];  // 8 KB
  int tid = threadIdx.x;
  // bucket-scatter slice (independent work; cnt zeroed by preceding memset)
  {
    int e0 = blockIdx.x * epb;
    int e1 = min(e0 + epb, E);
    for (int e = e0 + tid; e < e1; e += 256) {
      int d = dst[e];
      int pos = atomicAdd(&cnt[d], 1);
      if (pos < CAP) bucket[(size_t)d * CAP + pos] = src[e];
    }
  }
  int n0 = blockIdx.x * RM;
  int nrows = min(RM, N - n0);
  if (nrows <= 0) return;
  if (nrows == RM) {
    const float4* xg = (const float4*)(x + (size_t)n0 * INDIM);
    float4* xs4 = (float4*)xs;
    xs4[tid] = xg[tid];
    xs4[tid + 256] = xg[tid + 256];
  } else {
    for (int i = tid; i < RM * INDIM; i += 256) {
      int r = i / INDIM;
      xs[i] = (r < nrows) ? x[(size_t)(n0 + r) * INDIM + (i % INDIM)] : 0.f;
    }
  }
  __syncthreads();

  int lane = tid & 63;
  int wv = tid >> 6;
  int col = lane * 4;
  int row0 = wv * 4;

  float4 a0 = {0.f, 0.f, 0.f, 0.f}, a1 = a0, a2 = a0, a3 = a0;
  for (int k0 = 0; k0 < INDIM; k0 += 4) {
    float4 w0 = *(const float4*)&W[(size_t)(k0 + 0) * HC + col];
    float4 w1 = *(const float4*)&W[(size_t)(k0 + 1) * HC + col];
    float4 w2 = *(const float4*)&W[(size_t)(k0 + 2) * HC + col];
    float4 w3 = *(const float4*)&W[(size_t)(k0 + 3) * HC + col];
    float4 x0 = *(const float4*)&xs[(row0 + 0) * INDIM + k0];
    float4 x1v = *(const float4*)&xs[(row0 + 1) * INDIM + k0];
    float4 x2v = *(const float4*)&xs[(row0 + 2) * INDIM + k0];
    float4 x3v = *(const float4*)&xs[(row0 + 3) * INDIM + k0];
#define UPD(A, XV)                                                        \
    A.x = fmaf(XV.w, w3.x, fmaf(XV.z, w2.x, fmaf(XV.y, w1.x, fmaf(XV.x, w0.x, A.x)))); \
    A.y = fmaf(XV.w, w3.y, fmaf(XV.z, w2.y, fmaf(XV.y, w1.y, fmaf(XV.x, w0.y, A.y)))); \
    A.z = fmaf(XV.w, w3.z, fmaf(XV.z, w2.z, fmaf(XV.y, w1.z, fmaf(XV.x, w0.z, A.z)))); \
    A.w = fmaf(XV.w, w3.w, fmaf(XV.z, w2.w, fmaf(XV.y, w1.w, fmaf(XV.x, w0.w, A.w))))
    UPD(a0, x0);
    UPD(a1, x1v);
    UPD(a2, x2v);
    UPD(a3, x3v);
#undef UPD
  }

  float4 as4 = *(const float4*)&att_s[col];
  float4 ad4 = *(const float4*)&att_d[col];
  int h = lane >> 4;
  float4* accp[4] = {&a0, &a1, &a2, &a3};
#pragma unroll
  for (int r = 0; r < 4; ++r) {
    int row = row0 + r;
    if (row >= nrows) break;
    float4 a = *accp[r];
    uint2 pk;
    pk.x = f2bf_u(a.x) | (f2bf_u(a.y) << 16);
    pk.y = f2bf_u(a.z) | (f2bf_u(a.w) << 16);
    *(uint2*)&xpb[(size_t)(n0 + row) * HC + col] = pk;
    float ps = a.x * as4.x + a.y * as4.y + a.z * as4.z + a.w * as4.w;
    float pd = a.x * ad4.x + a.y * ad4.y + a.z * ad4.z + a.w * ad4.w;
#pragma unroll
    for (int o = 8; o > 0; o >>= 1) {
      ps += __shfl_xor(ps, o);
      pd += __shfl_xor(pd, o);
    }
    if ((lane & 15) == 0) {
      a_src[(n0 + row) * NH + h] = ps;
      a_dst[(n0 + row) * NH + h] = pd;
    }
  }
}

// ------- per-dst-node: softmax stats + bf16 gather aggregation -------
__global__ __launch_bounds__(256) void node_kernel(
    const int* __restrict__ cnt, const int* __restrict__ bucket,
    const float* __restrict__ a_src, const float* __restrict__ a_dst,
    const ushort_t* __restrict__ xpb, const float* __restrict__ bias,
    float* __restrict__ x1, float* __restrict__ mdi) {
  int n = blockIdx.x;
  int tid = threadIdx.x;
  int lane = tid & 63, wv = tid >> 6;
  int deg = min(cnt[n], CAP);
  float bv = bias[tid];
  if (deg == 0) { x1[(size_t)n * HC + tid] = bv; return; }
  const int* brow = bucket + (size_t)n * CAP;

  __shared__ float m_s[NH], d_s[NH];
  __shared__ __align__(16) float alpha_lds[NH * CAP];
  __shared__ __align__(16) int src_lds[CAP];

  // Phase A: wave wv = head wv online softmax (deg <= 128 -> <= 2 iters)
  {
    int h = wv;
    float adst = a_dst[n * NH + h];
    float m = -INFINITY, s = 0.f;
    for (int i = lane; i < deg; i += 64) {
      int sidx = brow[i];
      float l = a_src[sidx * NH + h] + adst;
      l = (l >= 0.f) ? l : 0.2f * l;
      if (l > m) { s = s * __expf(m - l) + 1.f; m = l; }
      else s += __expf(l - m);
    }
#pragma unroll
    for (int o = 32; o > 0; o >>= 1) {
      float m2 = __shfl_xor(m, o);
      float s2 = __shfl_xor(s, o);
      float M = fmaxf(m, m2);
      float sa = (m > -INFINITY) ? s * __expf(m - M) : 0.f;
      float sb = (m2 > -INFINITY) ? s2 * __expf(m2 - M) : 0.f;
      m = M; s = sa + sb;
    }
    if (lane == 0) { m_s[h] = m; d_s[h] = s + 1e-16f; }
  }
  __syncthreads();

  float m_r[NH], dinv_r[NH], adst_r[NH];
#pragma unroll
  for (int h = 0; h < NH; ++h) {
    m_r[h] = m_s[h];
    dinv_r[h] = 1.0f / d_s[h];
    adst_r[h] = a_dst[n * NH + h];
  }
  if (tid < NH) mdi[(size_t)n * 12 + tid] = m_r[tid];
  else if (tid < 2 * NH) mdi[(size_t)n * 12 + tid] = dinv_r[tid - NH];
  else if (tid < 3 * NH) mdi[(size_t)n * 12 + tid] = adst_r[tid - 2 * NH];

  // single chunk: deg <= CAP(128) < 256 threads
  int cpad = (deg + 3) & ~3;
  if (tid < deg) {
    int sidx = brow[tid];
    src_lds[tid] = sidx;
    float4 as4 = *(const float4*)&a_src[sidx * NH];
    const float* ap = (const float*)&as4;
#pragma unroll
    for (int h = 0; h < NH; ++h) {
      float l = ap[h] + adst_r[h];
      l = (l >= 0.f) ? l : 0.2f * l;
      alpha_lds[h * CAP + tid] = __expf(l - m_r[h]) * dinv_r[h];
    }
  } else if (tid < cpad) {
    src_lds[tid] = 0;
#pragma unroll
    for (int h = 0; h < NH; ++h) alpha_lds[h * CAP + tid] = 0.f;
  }
  __syncthreads();

  float acc0 = 0.f, acc1 = 0.f, acc2 = 0.f, acc3 = 0.f;
  int hbase = wv * CAP;
  for (int i = 0; i < cpad; i += 4) {
    float4 a4 = *(const float4*)&alpha_lds[hbase + i];
    int4 s4 = *(const int4*)&src_lds[i];
    ushort_t u0 = xpb[(size_t)s4.x * HC + tid];
    ushort_t u1 = xpb[(size_t)s4.y * HC + tid];
    ushort_t u2 = xpb[(size_t)s4.z * HC + tid];
    ushort_t u3 = xpb[(size_t)s4.w * HC + tid];
    acc0 = fmaf(a4.x, bf2f(u0), acc0);
    acc1 = fmaf(a4.y, bf2f(u1), acc1);
    acc2 = fmaf(a4.z, bf2f(u2), acc2);
    acc3 = fmaf(a4.w, bf2f(u3), acc3);
  }
  x1[(size_t)n * HC + tid] = (acc0 + acc1) + (acc2 + acc3) + bv;
}

// ------- fused: edge-order alpha (blocks [0,ab)) + BN1 stats (blocks [ab,..)) -------
__global__ __launch_bounds__(256) void alpha_bn1_kernel(
    const int* __restrict__ src, const int* __restrict__ dst,
    const float* __restrict__ a_src, const float* __restrict__ mdi,
    float* __restrict__ alpha_out, int E, int ab,
    const float* __restrict__ x1, float* __restrict__ sums, int N) {
  int tid = threadIdx.x;
  if ((int)blockIdx.x < ab) {
    int e = blockIdx.x * 256 + tid;
    if (e >= E) return;
    int s = src[e], d = dst[e];
    float4 as4 = *(const float4*)&a_src[s * NH];
    const float* md = &mdi[(size_t)d * 12];
    float4 m4 = *(const float4*)md;
    float4 di4 = *(const float4*)(md + 4);
    float4 ad4 = *(const float4*)(md + 8);
    const float* ap = (const float*)&as4;
    const float* mp = (const float*)&m4;
    const float* dp = (const float*)&di4;
    const float* adp = (const float*)&ad4;
    float4 av;
    float* avp = (float*)&av;
#pragma unroll
    for (int h = 0; h < NH; ++h) {
      float l = ap[h] + adp[h];
      l = (l >= 0.f) ? l : 0.2f * l;
      avp[h] = __expf(l - mp[h]) * dp[h];
    }
    *(float4*)&alpha_out[(size_t)e * NH] = av;
  } else {
    int b = blockIdx.x - ab;
    int r0 = b * BROWS;
    int rend = min(r0 + BROWS, N);
    float s = 0.f, q = 0.f;
    for (int r = r0; r < rend; ++r) {
      float v = x1[(size_t)r * HC + tid];
      s += v; q = fmaf(v, v, q);
    }
    atomicAdd(&sums[tid], s);
    atomicAdd(&sums[HC + tid], q);
  }
}

__global__ __launch_bounds__(256) void bn_stats2_kernel(
    const float* __restrict__ x1, const float* __restrict__ sums1,
    const float* __restrict__ gamma, const float* __restrict__ beta,
    float* __restrict__ sums2, int N) {
  int t = threadIdx.x;
  float mu = sums1[t] * (1.f / N);
  float var = sums1[HC + t] * (1.f / N) - mu * mu;
  float inv = rsqrtf(var + 1e-5f);
  float g = gamma[t], b = beta[t];
  int r0 = blockIdx.x * BROWS;
  int rend = min(r0 + BROWS, N);
  float s = 0.f, q = 0.f;
  for (int r = r0; r < rend; ++r) {
    float v = x1[(size_t)r * HC + t];
    float x2 = fmaf((v - mu) * inv, g, b);
    float e = x2 > 0.f ? x2 : expm1f(x2);
    s += e; q = fmaf(e, e, q);
  }
  atomicAdd(&sums2[t], s);
  atomicAdd(&sums2[HC + t], q);
}

__global__ __launch_bounds__(256) void bn_final_kernel(
    const float* __restrict__ x1, const float* __restrict__ sums1,
    const float* __restrict__ sums2, const float* __restrict__ gamma,
    const float* __restrict__ beta, float* __restrict__ out, int N) {
  int t = threadIdx.x;
  float mu1 = sums1[t] * (1.f / N);
  float var1 = sums1[HC + t] * (1.f / N) - mu1 * mu1;
  float inv1 = rsqrtf(var1 + 1e-5f);
  float mu2 = sums2[t] * (1.f / N);
  float var2 = sums2[HC + t] * (1.f / N) - mu2 * mu2;
  float inv2 = rsqrtf(var2 + 1e-5f);
  float g = gamma[t], b = beta[t];
  int h = t >> 6, c = t & 63;
  int r0 = blockIdx.x * BROWS;
  int rend = min(r0 + BROWS, N);
  for (int r = r0; r < rend; ++r) {
    float v = x1[(size_t)r * HC + t];
    float x2 = fmaf((v - mu1) * inv1, g, b);
    float e = x2 > 0.f ? x2 : expm1f(x2);
    out[(size_t)h * N * 64 + (size_t)r * 64 + c] = fmaf((e - mu2) * inv2, g, b);
  }
}

extern "C" void kernel_launch(void* const* d_in, const int* in_sizes, int n_in,
                              void* d_out, int out_size, void* d_ws, size_t ws_size,
                              hipStream_t stream) {
  const float* x     = (const float*)d_in[0];
  const int*   edge  = (const int*)d_in[1];
  const float* W     = (const float*)d_in[2];
  const float* att_s = (const float*)d_in[3];
  const float* att_d = (const float*)d_in[4];
  const float* bias  = (const float*)d_in[5];
  const float* gamma = (const float*)d_in[6];
  const float* beta  = (const float*)d_in[7];

  int N = in_sizes[0] / INDIM;
  int E = in_sizes[1] / 2;
  const int* src = edge;
  const int* dst = edge + E;

  char* ws = (char*)d_ws;
  size_t o = 0;
  auto alloc = [&](size_t bytes) {
    void* p = ws + o;
    o += (bytes + 255) & ~(size_t)255;
    return p;
  };
  ushort_t* xpb     = (ushort_t*)alloc((size_t)N * HC * 2);
  float* x1         = (float*)alloc((size_t)N * HC * 4);
  float* a_src      = (float*)alloc((size_t)N * NH * 4);
  float* a_dst      = (float*)alloc((size_t)N * NH * 4);
  float* mdi        = (float*)alloc((size_t)N * 12 * 4);
  // zero-init region: cnt + sums1 + sums2 contiguous -> single memset
  char*  zbase      = (char*)alloc(0);
  int*   cnt        = (int*)alloc((size_t)N * 4);
  float* sums1      = (float*)alloc(2 * HC * 4);
  float* sums2      = (float*)alloc(2 * HC * 4);
  size_t zbytes     = (size_t)((char*)alloc(0) - zbase);
  int*   bucket     = (int*)alloc((size_t)N * CAP * 4);

  float* out_heads = (float*)d_out;
  float* out_alpha = out_heads + (size_t)NH * N * 64;

  hipMemsetAsync(zbase, 0, zbytes, stream);

  int gblocks = (N + 15) / 16;
  int epb = (E + gblocks - 1) / gblocks;
  gemm_att_bucket_kernel<<<gblocks, 256, 0, stream>>>(
      x, W, att_s, att_d, src, dst, cnt, bucket, E, epb, xpb, a_src, a_dst, N);
  node_kernel<<<N, 256, 0, stream>>>(cnt, bucket, a_src, a_dst, xpb, bias, x1, mdi);
  int ab = (E + 255) / 256;
  int bnb = (N + BROWS - 1) / BROWS;
  alpha_bn1_kernel<<<ab + bnb, 256, 0, stream>>>(src, dst, a_src, mdi, out_alpha,
                                                 E, ab, x1, sums1, N);
  bn_stats2_kernel<<<bnb, 256, 0, stream>>>(x1, sums1, gamma, beta, sums2, N);
  bn_final_kernel<<<bnb, 256, 0, stream>>>(x1, sums1, sums2, gamma, beta, out_heads, N);
}

// Round 10
// 111.325 us; speedup vs baseline: 5.2794x; 1.1230x over previous
//
#include <hip/hip_runtime.h>
#include <math.h>

#define INDIM 128
#define HC 256
#define NH 4
#define CAP 128
#define NSHARD 64
#define BROWS 20

typedef unsigned short ushort_t;

__device__ __forceinline__ unsigned int f2bf_u(float f) {
  unsigned int u = __float_as_uint(f);
  return (u + 0x7FFFu + ((u >> 16) & 1u)) >> 16;
}
__device__ __forceinline__ float bf2f(ushort_t u) {
  return __uint_as_float(((unsigned int)u) << 16);
}

// --- GEMM (16x256 tile, 4x4 reg tile/thread) + att coeffs + bucket scatter ---
// bucket slot stores the EDGE ID (src recovered via src[e] in node_kernel).
__global__ __launch_bounds__(256) void gemm_att_bucket_kernel(
    const float* __restrict__ x, const float* __restrict__ W,
    const float* __restrict__ att_s, const float* __restrict__ att_d,
    const int* __restrict__ dst, int* __restrict__ cnt,
    int* __restrict__ bucket, int E, int epb, ushort_t* __restrict__ xpb,
    float* __restrict__ a_src, float* __restrict__ a_dst, int N) {
  constexpr int RM = 16;
  __shared__ __align__(16) float xs[RM * INDIM];  // 8 KB
  int tid = threadIdx.x;
  // bucket-scatter slice (independent work; cnt zeroed by preceding memset)
  {
    int e0 = blockIdx.x * epb;
    int e1 = min(e0 + epb, E);
    for (int e = e0 + tid; e < e1; e += 256) {
      int d = dst[e];
      int pos = atomicAdd(&cnt[d], 1);
      if (pos < CAP) bucket[(size_t)d * CAP + pos] = e;
    }
  }
  int n0 = blockIdx.x * RM;
  int nrows = min(RM, N - n0);
  if (nrows <= 0) return;
  if (nrows == RM) {
    const float4* xg = (const float4*)(x + (size_t)n0 * INDIM);
    float4* xs4 = (float4*)xs;
    xs4[tid] = xg[tid];
    xs4[tid + 256] = xg[tid + 256];
  } else {
    for (int i = tid; i < RM * INDIM; i += 256) {
      int r = i / INDIM;
      xs[i] = (r < nrows) ? x[(size_t)(n0 + r) * INDIM + (i % INDIM)] : 0.f;
    }
  }
  __syncthreads();

  int lane = tid & 63;
  int wv = tid >> 6;
  int col = lane * 4;
  int row0 = wv * 4;

  float4 a0 = {0.f, 0.f, 0.f, 0.f}, a1 = a0, a2 = a0, a3 = a0;
  for (int k0 = 0; k0 < INDIM; k0 += 4) {
    float4 w0 = *(const float4*)&W[(size_t)(k0 + 0) * HC + col];
    float4 w1 = *(const float4*)&W[(size_t)(k0 + 1) * HC + col];
    float4 w2 = *(const float4*)&W[(size_t)(k0 + 2) * HC + col];
    float4 w3 = *(const float4*)&W[(size_t)(k0 + 3) * HC + col];
    float4 x0 = *(const float4*)&xs[(row0 + 0) * INDIM + k0];
    float4 x1v = *(const float4*)&xs[(row0 + 1) * INDIM + k0];
    float4 x2v = *(const float4*)&xs[(row0 + 2) * INDIM + k0];
    float4 x3v = *(const float4*)&xs[(row0 + 3) * INDIM + k0];
#define UPD(A, XV)                                                        \
    A.x = fmaf(XV.w, w3.x, fmaf(XV.z, w2.x, fmaf(XV.y, w1.x, fmaf(XV.x, w0.x, A.x)))); \
    A.y = fmaf(XV.w, w3.y, fmaf(XV.z, w2.y, fmaf(XV.y, w1.y, fmaf(XV.x, w0.y, A.y)))); \
    A.z = fmaf(XV.w, w3.z, fmaf(XV.z, w2.z, fmaf(XV.y, w1.z, fmaf(XV.x, w0.z, A.z)))); \
    A.w = fmaf(XV.w, w3.w, fmaf(XV.z, w2.w, fmaf(XV.y, w1.w, fmaf(XV.x, w0.w, A.w))))
    UPD(a0, x0);
    UPD(a1, x1v);
    UPD(a2, x2v);
    UPD(a3, x3v);
#undef UPD
  }

  float4 as4 = *(const float4*)&att_s[col];
  float4 ad4 = *(const float4*)&att_d[col];
  int h = lane >> 4;
  float4* accp[4] = {&a0, &a1, &a2, &a3};
#pragma unroll
  for (int r = 0; r < 4; ++r) {
    int row = row0 + r;
    if (row >= nrows) break;
    float4 a = *accp[r];
    uint2 pk;
    pk.x = f2bf_u(a.x) | (f2bf_u(a.y) << 16);
    pk.y = f2bf_u(a.z) | (f2bf_u(a.w) << 16);
    *(uint2*)&xpb[(size_t)(n0 + row) * HC + col] = pk;
    float ps = a.x * as4.x + a.y * as4.y + a.z * as4.z + a.w * as4.w;
    float pd = a.x * ad4.x + a.y * ad4.y + a.z * ad4.z + a.w * ad4.w;
#pragma unroll
    for (int o = 8; o > 0; o >>= 1) {
      ps += __shfl_xor(ps, o);
      pd += __shfl_xor(pd, o);
    }
    if ((lane & 15) == 0) {
      a_src[(n0 + row) * NH + h] = ps;
      a_dst[(n0 + row) * NH + h] = pd;
    }
  }
}

// ------- per-dst-node: softmax + bf16 gather aggregation + alpha scatter
//         + sharded BN1 stats (64 shards -> ~156 RMWs/address, no hotspot) -------
__global__ __launch_bounds__(256) void node_kernel(
    const int* __restrict__ cnt, const int* __restrict__ bucket,
    const int* __restrict__ src_arr, const float* __restrict__ a_src,
    const float* __restrict__ a_dst, const ushort_t* __restrict__ xpb,
    const float* __restrict__ bias, float* __restrict__ x1,
    float* __restrict__ alpha_out, float* __restrict__ shards, int N) {
  int n = blockIdx.x;
  int tid = threadIdx.x;
  int lane = tid & 63, wv = tid >> 6;
  int deg = min(cnt[n], CAP);
  float bv = bias[tid];
  int shb = (n & (NSHARD - 1)) * (2 * HC);
  if (deg == 0) {
    x1[(size_t)n * HC + tid] = bv;
    atomicAdd(&shards[shb + tid], bv);
    atomicAdd(&shards[shb + HC + tid], bv * bv);
    return;
  }
  const int* brow = bucket + (size_t)n * CAP;

  __shared__ float m_s[NH], d_s[NH];
  __shared__ __align__(16) float alpha_lds[NH * CAP];
  __shared__ __align__(16) int src_lds[CAP];

  // Phase A: wave wv = head wv online softmax; wave 0 caches src indices in LDS
  {
    int h = wv;
    float adst = a_dst[n * NH + h];
    float m = -INFINITY, s = 0.f;
    for (int i = lane; i < deg; i += 64) {
      int sidx = src_arr[brow[i]];
      if (h == 0) src_lds[i] = sidx;
      float l = a_src[sidx * NH + h] + adst;
      l = (l >= 0.f) ? l : 0.2f * l;
      if (l > m) { s = s * __expf(m - l) + 1.f; m = l; }
      else s += __expf(l - m);
    }
#pragma unroll
    for (int o = 32; o > 0; o >>= 1) {
      float m2 = __shfl_xor(m, o);
      float s2 = __shfl_xor(s, o);
      float M = fmaxf(m, m2);
      float sa = (m > -INFINITY) ? s * __expf(m - M) : 0.f;
      float sb = (m2 > -INFINITY) ? s2 * __expf(m2 - M) : 0.f;
      m = M; s = sa + sb;
    }
    if (lane == 0) { m_s[h] = m; d_s[h] = s + 1e-16f; }
  }
  __syncthreads();

  float m_r[NH], dinv_r[NH], adst_r[NH];
#pragma unroll
  for (int h = 0; h < NH; ++h) {
    m_r[h] = m_s[h];
    dinv_r[h] = 1.0f / d_s[h];
    adst_r[h] = a_dst[n * NH + h];
  }

  // alpha: one edge per thread (deg <= CAP=128 < 256); scatter to out + LDS
  int cpad = (deg + 3) & ~3;
  if (tid < deg) {
    int sidx = src_lds[tid];
    float4 as4 = *(const float4*)&a_src[sidx * NH];
    const float* ap = (const float*)&as4;
    float4 av;
    float* avp = (float*)&av;
#pragma unroll
    for (int h = 0; h < NH; ++h) {
      float l = ap[h] + adst_r[h];
      l = (l >= 0.f) ? l : 0.2f * l;
      float a = __expf(l - m_r[h]) * dinv_r[h];
      alpha_lds[h * CAP + tid] = a;
      avp[h] = a;
    }
    *(float4*)&alpha_out[(size_t)brow[tid] * NH] = av;
  } else if (tid < cpad) {
    src_lds[tid] = 0;
#pragma unroll
    for (int h = 0; h < NH; ++h) alpha_lds[h * CAP + tid] = 0.f;
  }
  __syncthreads();

  float acc0 = 0.f, acc1 = 0.f, acc2 = 0.f, acc3 = 0.f;
  int hbase = wv * CAP;
  for (int i = 0; i < cpad; i += 4) {
    float4 a4 = *(const float4*)&alpha_lds[hbase + i];
    int4 s4 = *(const int4*)&src_lds[i];
    ushort_t u0 = xpb[(size_t)s4.x * HC + tid];
    ushort_t u1 = xpb[(size_t)s4.y * HC + tid];
    ushort_t u2 = xpb[(size_t)s4.z * HC + tid];
    ushort_t u3 = xpb[(size_t)s4.w * HC + tid];
    acc0 = fmaf(a4.x, bf2f(u0), acc0);
    acc1 = fmaf(a4.y, bf2f(u1), acc1);
    acc2 = fmaf(a4.z, bf2f(u2), acc2);
    acc3 = fmaf(a4.w, bf2f(u3), acc3);
  }
  float v = (acc0 + acc1) + (acc2 + acc3) + bv;
  x1[(size_t)n * HC + tid] = v;
  atomicAdd(&shards[shb + tid], v);
  atomicAdd(&shards[shb + HC + tid], v * v);
}

// ------- BN2 stats: reduce BN1 shards in-register, then pass over elu(bn1(x1)) -------
__global__ __launch_bounds__(256) void bn_stats2_kernel(
    const float* __restrict__ x1, const float* __restrict__ shards,
    const float* __restrict__ gamma, const float* __restrict__ beta,
    float* __restrict__ sums2, int N) {
  int t = threadIdx.x;
  float s1 = 0.f, q1 = 0.f;
#pragma unroll
  for (int k = 0; k < NSHARD; ++k) {
    s1 += shards[k * (2 * HC) + t];
    q1 += shards[k * (2 * HC) + HC + t];
  }
  float mu = s1 * (1.f / N);
  float var = q1 * (1.f / N) - mu * mu;
  float inv = rsqrtf(var + 1e-5f);
  float g = gamma[t], b = beta[t];
  int r0 = blockIdx.x * BROWS;
  int rend = min(r0 + BROWS, N);
  float s = 0.f, q = 0.f;
  for (int r = r0; r < rend; ++r) {
    float v = x1[(size_t)r * HC + t];
    float x2 = fmaf((v - mu) * inv, g, b);
    float e = x2 > 0.f ? x2 : expm1f(x2);
    s += e; q = fmaf(e, e, q);
  }
  atomicAdd(&sums2[t], s);
  atomicAdd(&sums2[HC + t], q);
}

// ------- final: shard-reduce BN1, read sums2, apply both BNs, transposed store -------
__global__ __launch_bounds__(256) void bn_final_kernel(
    const float* __restrict__ x1, const float* __restrict__ shards,
    const float* __restrict__ sums2, const float* __restrict__ gamma,
    const float* __restrict__ beta, float* __restrict__ out, int N) {
  int t = threadIdx.x;
  float s1 = 0.f, q1 = 0.f;
#pragma unroll
  for (int k = 0; k < NSHARD; ++k) {
    s1 += shards[k * (2 * HC) + t];
    q1 += shards[k * (2 * HC) + HC + t];
  }
  float mu1 = s1 * (1.f / N);
  float var1 = q1 * (1.f / N) - mu1 * mu1;
  float inv1 = rsqrtf(var1 + 1e-5f);
  float mu2 = sums2[t] * (1.f / N);
  float var2 = sums2[HC + t] * (1.f / N) - mu2 * mu2;
  float inv2 = rsqrtf(var2 + 1e-5f);
  float g = gamma[t], b = beta[t];
  int h = t >> 6, c = t & 63;
  int r0 = blockIdx.x * BROWS;
  int rend = min(r0 + BROWS, N);
  for (int r = r0; r < rend; ++r) {
    float v = x1[(size_t)r * HC + t];
    float x2 = fmaf((v - mu1) * inv1, g, b);
    float e = x2 > 0.f ? x2 : expm1f(x2);
    out[(size_t)h * N * 64 + (size_t)r * 64 + c] = fmaf((e - mu2) * inv2, g, b);
  }
}

extern "C" void kernel_launch(void* const* d_in, const int* in_sizes, int n_in,
                              void* d_out, int out_size, void* d_ws, size_t ws_size,
                              hipStream_t stream) {
  const float* x     = (const float*)d_in[0];
  const int*   edge  = (const int*)d_in[1];
  const float* W     = (const float*)d_in[2];
  const float* att_s = (const float*)d_in[3];
  const float* att_d = (const float*)d_in[4];
  const float* bias  = (const float*)d_in[5];
  const float* gamma = (const float*)d_in[6];
  const float* beta  = (const float*)d_in[7];

  int N = in_sizes[0] / INDIM;
  int E = in_sizes[1] / 2;
  const int* src = edge;
  const int* dst = edge + E;

  char* ws = (char*)d_ws;
  size_t o = 0;
  auto alloc = [&](size_t bytes) {
    void* p = ws + o;
    o += (bytes + 255) & ~(size_t)255;
    return p;
  };
  ushort_t* xpb     = (ushort_t*)alloc((size_t)N * HC * 2);
  float* x1         = (float*)alloc((size_t)N * HC * 4);
  float* a_src      = (float*)alloc((size_t)N * NH * 4);
  float* a_dst      = (float*)alloc((size_t)N * NH * 4);
  // zero-init region: cnt + shards + sums2 contiguous -> single memset
  char*  zbase      = (char*)alloc(0);
  int*   cnt        = (int*)alloc((size_t)N * 4);
  float* shards     = (float*)alloc((size_t)NSHARD * 2 * HC * 4);
  float* sums2      = (float*)alloc(2 * HC * 4);
  size_t zbytes     = (size_t)((char*)alloc(0) - zbase);
  int*   bucket     = (int*)alloc((size_t)N * CAP * 4);

  float* out_heads = (float*)d_out;
  float* out_alpha = out_heads + (size_t)NH * N * 64;

  hipMemsetAsync(zbase, 0, zbytes, stream);

  int gblocks = (N + 15) / 16;
  int epb = (E + gblocks - 1) / gblocks;
  gemm_att_bucket_kernel<<<gblocks, 256, 0, stream>>>(
      x, W, att_s, att_d, dst, cnt, bucket, E, epb, xpb, a_src, a_dst, N);
  node_kernel<<<N, 256, 0, stream>>>(cnt, bucket, src, a_src, a_dst, xpb, bias,
                                     x1, out_alpha, shards, N);
  int bnb = (N + BROWS - 1) / BROWS;
  bn_stats2_kernel<<<bnb, 256, 0, stream>>>(x1, shards, gamma, beta, sums2, N);
  bn_final_kernel<<<bnb, 256, 0, stream>>>(x1, shards, sums2, gamma, beta,
                                           out_heads, N);
}